// Round 2
// baseline (826.785 us; speedup 1.0000x reference)
//
#include <hip/hip_runtime.h>
#include <math.h>

#define VOCAB 100000
#define BATCH 4096
#define DOC_LEN 200
#define EMBED_DIM 300
#define NUM_CLASSES 20

// ---------------------------------------------------------------------------
// Kernel 1:  P[v][c] = (1/DOC_LEN) * sum_k emb[v][k] * W[c][k]
// 5 waves/block = 5 K-slices of 60 dims (240 B offsets keep float4 align).
// Each lane owns 2 rows -> W broadcast reads amortize over 2 rows.
// Grid 782 blocks -> ~15 waves/CU (vs 3 before). Slice partials reduced
// through LDS (stride 21 = bank-conflict-free), aliased over the W buffer.
// ---------------------------------------------------------------------------
#define K1_BLOCK 320
#define K1_ROWS  128                                   // rows per block
#define K1_GRID  ((VOCAB + K1_ROWS - 1) / K1_ROWS)     // 782

__global__ __launch_bounds__(K1_BLOCK, 4) void project_kernel(
    const float* __restrict__ emb,   // (VOCAB, 300)
    const float* __restrict__ W,     // (20, 300)
    float*       __restrict__ P)     // (VOCAB, 20)  [workspace]
{
    // union: sW (6000 floats) during compute; partials [5][128][21] after
    __shared__ float smem[5 * K1_ROWS * 21];           // 53760 B

    float* sW = smem;
    for (int i = threadIdx.x; i < NUM_CLASSES * EMBED_DIM; i += K1_BLOCK)
        sW[i] = W[i];
    __syncthreads();

    const int s     = threadIdx.x >> 6;                // slice = wave id, 0..4
    const int lane  = threadIdx.x & 63;
    const int rbase = blockIdx.x * K1_ROWS;
    const int r0 = rbase + lane;
    const int r1 = rbase + lane + 64;
    const float* e0 = emb + (size_t)(r0 < VOCAB ? r0 : VOCAB - 1) * EMBED_DIM + s * 60;
    const float* e1 = emb + (size_t)(r1 < VOCAB ? r1 : VOCAB - 1) * EMBED_DIM + s * 60;
    const float* wS = sW + s * 60;

    float acc0[NUM_CLASSES], acc1[NUM_CLASSES];
    #pragma unroll
    for (int c = 0; c < NUM_CLASSES; ++c) { acc0[c] = 0.0f; acc1[c] = 0.0f; }

    // 60 dims = 5 chunks x 12 floats (3 float4 per row per chunk)
    #pragma unroll
    for (int k = 0; k < 60; k += 12) {
        const float4 a0 = *reinterpret_cast<const float4*>(e0 + k);
        const float4 a1 = *reinterpret_cast<const float4*>(e0 + k + 4);
        const float4 a2 = *reinterpret_cast<const float4*>(e0 + k + 8);
        const float4 b0 = *reinterpret_cast<const float4*>(e1 + k);
        const float4 b1 = *reinterpret_cast<const float4*>(e1 + k + 4);
        const float4 b2 = *reinterpret_cast<const float4*>(e1 + k + 8);
        #pragma unroll
        for (int c = 0; c < NUM_CLASSES; ++c) {
            const float* wc = wS + c * EMBED_DIM + k;  // wave-uniform -> broadcast
            const float4 w0 = *reinterpret_cast<const float4*>(wc);
            const float4 w1 = *reinterpret_cast<const float4*>(wc + 4);
            const float4 w2 = *reinterpret_cast<const float4*>(wc + 8);
            acc0[c] += a0.x*w0.x + a0.y*w0.y + a0.z*w0.z + a0.w*w0.w
                     + a1.x*w1.x + a1.y*w1.y + a1.z*w1.z + a1.w*w1.w
                     + a2.x*w2.x + a2.y*w2.y + a2.z*w2.z + a2.w*w2.w;
            acc1[c] += b0.x*w0.x + b0.y*w0.y + b0.z*w0.z + b0.w*w0.w
                     + b1.x*w1.x + b1.y*w1.y + b1.z*w1.z + b1.w*w1.w
                     + b2.x*w2.x + b2.y*w2.y + b2.z*w2.z + b2.w*w2.w;
        }
    }
    __syncthreads();   // everyone done reading sW

    // partials: [s][r][21]; stride 21 is coprime with 32 banks
    float* sPart = smem;
    #pragma unroll
    for (int c = 0; c < NUM_CLASSES; ++c) {
        sPart[(s * K1_ROWS + lane) * 21 + c]      = acc0[c];
        sPart[(s * K1_ROWS + lane + 64) * 21 + c] = acc1[c];
    }
    __syncthreads();

    // reduce 5 slices; 2560 outputs, 8 per thread; coalesced float stores
    const float inv = 1.0f / (float)DOC_LEN;
    #pragma unroll
    for (int j = 0; j < 8; ++j) {
        const int oi = threadIdx.x + j * K1_BLOCK;     // 0..2559
        const int r  = oi / NUM_CLASSES;
        const int c  = oi - r * NUM_CLASSES;
        float v = 0.0f;
        #pragma unroll
        for (int ss = 0; ss < 5; ++ss)
            v += sPart[(ss * K1_ROWS + r) * 21 + c];
        const int gr = rbase + r;
        if (gr < VOCAB)
            P[(size_t)gr * NUM_CLASSES + c] = v * inv;
    }
}

// ---------------------------------------------------------------------------
// Kernel 2: out[doc] = softmax( sum_l P[x[doc][l]] + b )   (unchanged)
// ---------------------------------------------------------------------------
#define K2_BLOCK 256
#define DOCS_PER_BLOCK 4

__global__ __launch_bounds__(K2_BLOCK) void pool_softmax_kernel(
    const float* __restrict__ P,     // (VOCAB, 20), pre-scaled by 1/DOC_LEN
    const float* __restrict__ bias,  // (20,)
    const int*   __restrict__ x,     // (BATCH, 200)
    float*       __restrict__ out)   // (BATCH, 20)
{
    __shared__ int sidx[DOCS_PER_BLOCK][DOC_LEN];

    const int doc0 = blockIdx.x * DOCS_PER_BLOCK;
    const int tid  = threadIdx.x;

    for (int i = tid; i < DOCS_PER_BLOCK * DOC_LEN; i += K2_BLOCK)
        (&sidx[0][0])[i] = x[doc0 * DOC_LEN + i];
    __syncthreads();

    const int wave = tid >> 6;
    const int lane = tid & 63;
    const int doc  = doc0 + wave;
    const int g    = lane / NUM_CLASSES;          // 0..2 active, 3 idle
    const int c    = lane - g * NUM_CLASSES;

    float acc = 0.0f;
    if (g < 3) {
        #pragma unroll 4
        for (int l = g; l < DOC_LEN; l += 3) {
            const int row = sidx[wave][l];        // LDS broadcast per group
            acc += P[(size_t)row * NUM_CLASSES + c];
        }
    }

    const float a1 = __shfl(acc, lane + 20, 64);
    const float a2 = __shfl(acc, lane + 40, 64);

    float v = (lane < NUM_CLASSES) ? (acc + a1 + a2 + bias[c]) : -INFINITY;

    float m = v;
    #pragma unroll
    for (int off = 16; off > 0; off >>= 1)
        m = fmaxf(m, __shfl_xor(m, off, 32));
    const float e = (lane < NUM_CLASSES) ? expf(v - m) : 0.0f;
    float s = e;
    #pragma unroll
    for (int off = 16; off > 0; off >>= 1)
        s += __shfl_xor(s, off, 32);

    if (lane < NUM_CLASSES)
        out[doc * NUM_CLASSES + lane] = e / s;
}

extern "C" void kernel_launch(void* const* d_in, const int* in_sizes, int n_in,
                              void* d_out, int out_size, void* d_ws, size_t ws_size,
                              hipStream_t stream) {
    const float* emb  = (const float*)d_in[0];
    const float* W    = (const float*)d_in[1];
    const float* bias = (const float*)d_in[2];
    const int*   x    = (const int*)d_in[3];
    float* out = (float*)d_out;
    float* P   = (float*)d_ws;   // needs VOCAB*20*4 = 8,000,000 B

    project_kernel<<<K1_GRID, K1_BLOCK, 0, stream>>>(emb, W, P);
    pool_softmax_kernel<<<BATCH / DOCS_PER_BLOCK, K2_BLOCK, 0, stream>>>(P, bias, x, out);
}

// Round 3
// 103.484 us; speedup vs baseline: 7.9895x; 7.9895x over previous
//
#include <hip/hip_runtime.h>
#include <math.h>

#define VOCAB 100000
#define BATCH 4096
#define DOC_LEN 200
#define EMBED_DIM 300
#define NUM_CLASSES 20

// ---------------------------------------------------------------------------
// Kernel 1:  P[v][c] = (1/DOC_LEN) * sum_k emb[v][k] * W[c][k]
// Class-split parallelism: thread = (row, class-group-of-4).
// Block = 320 threads = 5 waves; wave cg owns classes 4cg..4cg+3; lanes = 64
// consecutive rows. 1563 blocks -> 7812 waves (~30/CU, vs 3 in round 1).
// Per-thread state: 4 accumulators -> no spill risk (round-2 post-mortem).
// W reads are wave-uniform (readfirstlane'd cg) -> scalar s_load path, no LDS.
// All 5 waves of a block stream the SAME 64 rows -> L1/L2 absorbs the 5x
// logical re-read; HBM traffic stays ~120 MB.
// ---------------------------------------------------------------------------
#define K1_BLOCK 320
#define K1_ROWS  64
#define K1_GRID  ((VOCAB + K1_ROWS - 1) / K1_ROWS)   // 1563

__global__ __launch_bounds__(K1_BLOCK) void project_kernel(
    const float* __restrict__ emb,   // (VOCAB, 300)
    const float* __restrict__ W,     // (20, 300)
    float*       __restrict__ P)     // (VOCAB, 20)  [workspace]
{
    const int lane = threadIdx.x & 63;
    const int cg   = __builtin_amdgcn_readfirstlane(threadIdx.x >> 6);  // 0..4, SGPR
    const int row  = blockIdx.x * K1_ROWS + lane;
    const int rrow = row < VOCAB ? row : VOCAB - 1;     // clamp reads only
    const float* __restrict__ e = emb + (size_t)rrow * EMBED_DIM;
    const float* __restrict__ w = W + (size_t)cg * 4 * EMBED_DIM;

    float acc0 = 0.0f, acc1 = 0.0f, acc2 = 0.0f, acc3 = 0.0f;

    // 300 dims = 25 chunks of 12 floats (3 x float4 per chunk)
    #pragma unroll 5
    for (int k = 0; k < EMBED_DIM; k += 12) {
        const float4 a0 = *reinterpret_cast<const float4*>(e + k);
        const float4 a1 = *reinterpret_cast<const float4*>(e + k + 4);
        const float4 a2 = *reinterpret_cast<const float4*>(e + k + 8);

        #pragma unroll
        for (int cc = 0; cc < 4; ++cc) {
            const float* wc = w + cc * EMBED_DIM + k;   // uniform addr -> s_load
            const float4 w0 = *reinterpret_cast<const float4*>(wc);
            const float4 w1 = *reinterpret_cast<const float4*>(wc + 4);
            const float4 w2 = *reinterpret_cast<const float4*>(wc + 8);
            const float d = a0.x*w0.x + a0.y*w0.y + a0.z*w0.z + a0.w*w0.w
                          + a1.x*w1.x + a1.y*w1.y + a1.z*w1.z + a1.w*w1.w
                          + a2.x*w2.x + a2.y*w2.y + a2.z*w2.z + a2.w*w2.w;
            if (cc == 0) acc0 += d;
            else if (cc == 1) acc1 += d;
            else if (cc == 2) acc2 += d;
            else acc3 += d;
        }
    }

    if (row < VOCAB) {
        const float inv = 1.0f / (float)DOC_LEN;        // fold mean into P
        const float4 r = make_float4(acc0 * inv, acc1 * inv, acc2 * inv, acc3 * inv);
        // (row*20 + 4*cg) is a multiple of 4 -> 16B-aligned float4 store
        *reinterpret_cast<float4*>(P + (size_t)row * NUM_CLASSES + cg * 4) = r;
    }
}

// ---------------------------------------------------------------------------
// Kernel 2: out[doc] = softmax( sum_l P[x[doc][l]] + b )   (unchanged)
// One wave per doc; 64 lanes = 3 position-groups x 20 classes.
// ---------------------------------------------------------------------------
#define K2_BLOCK 256
#define DOCS_PER_BLOCK 4

__global__ __launch_bounds__(K2_BLOCK) void pool_softmax_kernel(
    const float* __restrict__ P,     // (VOCAB, 20), pre-scaled by 1/DOC_LEN
    const float* __restrict__ bias,  // (20,)
    const int*   __restrict__ x,     // (BATCH, 200)
    float*       __restrict__ out)   // (BATCH, 20)
{
    __shared__ int sidx[DOCS_PER_BLOCK][DOC_LEN];

    const int doc0 = blockIdx.x * DOCS_PER_BLOCK;
    const int tid  = threadIdx.x;

    for (int i = tid; i < DOCS_PER_BLOCK * DOC_LEN; i += K2_BLOCK)
        (&sidx[0][0])[i] = x[doc0 * DOC_LEN + i];
    __syncthreads();

    const int wave = tid >> 6;
    const int lane = tid & 63;
    const int doc  = doc0 + wave;
    const int g    = lane / NUM_CLASSES;          // 0..2 active, 3 idle
    const int c    = lane - g * NUM_CLASSES;

    float acc = 0.0f;
    if (g < 3) {
        #pragma unroll 4
        for (int l = g; l < DOC_LEN; l += 3) {
            const int row = sidx[wave][l];        // LDS broadcast per group
            acc += P[(size_t)row * NUM_CLASSES + c];
        }
    }

    const float a1 = __shfl(acc, lane + 20, 64);
    const float a2 = __shfl(acc, lane + 40, 64);

    float v = (lane < NUM_CLASSES) ? (acc + a1 + a2 + bias[c]) : -INFINITY;

    float m = v;
    #pragma unroll
    for (int off = 16; off > 0; off >>= 1)
        m = fmaxf(m, __shfl_xor(m, off, 32));
    const float e = (lane < NUM_CLASSES) ? expf(v - m) : 0.0f;
    float s = e;
    #pragma unroll
    for (int off = 16; off > 0; off >>= 1)
        s += __shfl_xor(s, off, 32);

    if (lane < NUM_CLASSES)
        out[doc * NUM_CLASSES + lane] = e / s;
}

extern "C" void kernel_launch(void* const* d_in, const int* in_sizes, int n_in,
                              void* d_out, int out_size, void* d_ws, size_t ws_size,
                              hipStream_t stream) {
    const float* emb  = (const float*)d_in[0];
    const float* W    = (const float*)d_in[1];
    const float* bias = (const float*)d_in[2];
    const int*   x    = (const int*)d_in[3];
    float* out = (float*)d_out;
    float* P   = (float*)d_ws;   // needs VOCAB*20*4 = 8,000,000 B

    project_kernel<<<K1_GRID, K1_BLOCK, 0, stream>>>(emb, W, P);
    pool_softmax_kernel<<<BATCH / DOCS_PER_BLOCK, K2_BLOCK, 0, stream>>>(P, bias, x, out);
}

// Round 4
// 91.630 us; speedup vs baseline: 9.0231x; 1.1294x over previous
//
#include <hip/hip_runtime.h>
#include <math.h>

#define VOCAB 100000
#define BATCH 4096
#define DOC_LEN 200
#define EMBED_DIM 300
#define NUM_CLASSES 20

// ---------------------------------------------------------------------------
// Kernel 1:  P[v][c] = (1/DOC_LEN) * sum_k emb[v][k] * W[c][k]
// Class-split (5 waves = 5 class-groups of 4) for occupancy + tiny acc state,
// W in LDS (uniform-address ds_read_b128 = HW broadcast, no scalar-K$ path —
// round-3 post-mortem: s_load K$ thrash was the stall), R=2 rows/thread to
// amortize the LDS reads (12 ds_read_b128 per 96 lane-FMAs per chunk).
// Grid 782 x 320 = 3910 waves (~15/CU). No min-waves launch bound (round 2).
// ---------------------------------------------------------------------------
#define K1_BLOCK 320
#define K1_RPB   128                                  // rows per block
#define K1_GRID  ((VOCAB + K1_RPB - 1) / K1_RPB)      // 782

__global__ __launch_bounds__(K1_BLOCK) void project_kernel(
    const float* __restrict__ emb,   // (VOCAB, 300)
    const float* __restrict__ W,     // (20, 300)
    float*       __restrict__ P)     // (VOCAB, 20)  [workspace]
{
    __shared__ float sW[NUM_CLASSES * EMBED_DIM];     // 24000 B, class-major

    for (int i = threadIdx.x; i < NUM_CLASSES * EMBED_DIM; i += K1_BLOCK)
        sW[i] = W[i];
    __syncthreads();

    const int lane = threadIdx.x & 63;
    const int cg   = __builtin_amdgcn_readfirstlane(threadIdx.x >> 6); // 0..4
    const int r0   = blockIdx.x * K1_RPB + lane;
    const int r1   = r0 + 64;
    const float* __restrict__ e0 = emb + (size_t)(r0 < VOCAB ? r0 : VOCAB - 1) * EMBED_DIM;
    const float* __restrict__ e1 = emb + (size_t)(r1 < VOCAB ? r1 : VOCAB - 1) * EMBED_DIM;
    const float* wS = sW + cg * 4 * EMBED_DIM;        // this wave's 4 classes

    float acc0[4] = {0.f, 0.f, 0.f, 0.f};
    float acc1[4] = {0.f, 0.f, 0.f, 0.f};

    // 300 dims = 25 chunks of 12 floats (3 x float4 per row per chunk)
    #pragma unroll 5
    for (int k = 0; k < EMBED_DIM; k += 12) {
        const float4 a0 = *reinterpret_cast<const float4*>(e0 + k);
        const float4 a1 = *reinterpret_cast<const float4*>(e0 + k + 4);
        const float4 a2 = *reinterpret_cast<const float4*>(e0 + k + 8);
        const float4 b0 = *reinterpret_cast<const float4*>(e1 + k);
        const float4 b1 = *reinterpret_cast<const float4*>(e1 + k + 4);
        const float4 b2 = *reinterpret_cast<const float4*>(e1 + k + 8);

        #pragma unroll
        for (int cc = 0; cc < 4; ++cc) {
            const float* wc = wS + cc * EMBED_DIM + k;   // wave-uniform -> broadcast
            const float4 w0 = *reinterpret_cast<const float4*>(wc);
            const float4 w1 = *reinterpret_cast<const float4*>(wc + 4);
            const float4 w2 = *reinterpret_cast<const float4*>(wc + 8);
            acc0[cc] += a0.x*w0.x + a0.y*w0.y + a0.z*w0.z + a0.w*w0.w
                      + a1.x*w1.x + a1.y*w1.y + a1.z*w1.z + a1.w*w1.w
                      + a2.x*w2.x + a2.y*w2.y + a2.z*w2.z + a2.w*w2.w;
            acc1[cc] += b0.x*w0.x + b0.y*w0.y + b0.z*w0.z + b0.w*w0.w
                      + b1.x*w1.x + b1.y*w1.y + b1.z*w1.z + b1.w*w1.w
                      + b2.x*w2.x + b2.y*w2.y + b2.z*w2.z + b2.w*w2.w;
        }
    }

    const float inv = 1.0f / (float)DOC_LEN;          // fold mean into P
    if (r0 < VOCAB) {
        const float4 v = make_float4(acc0[0]*inv, acc0[1]*inv, acc0[2]*inv, acc0[3]*inv);
        *reinterpret_cast<float4*>(P + (size_t)r0 * NUM_CLASSES + cg * 4) = v;
    }
    if (r1 < VOCAB) {
        const float4 v = make_float4(acc1[0]*inv, acc1[1]*inv, acc1[2]*inv, acc1[3]*inv);
        *reinterpret_cast<float4*>(P + (size_t)r1 * NUM_CLASSES + cg * 4) = v;
    }
}

// ---------------------------------------------------------------------------
// Kernel 2: out[doc] = softmax( sum_l P[x[doc][l]] + b )   (unchanged)
// One wave per doc; 64 lanes = 3 position-groups x 20 classes.
// ---------------------------------------------------------------------------
#define K2_BLOCK 256
#define DOCS_PER_BLOCK 4

__global__ __launch_bounds__(K2_BLOCK) void pool_softmax_kernel(
    const float* __restrict__ P,     // (VOCAB, 20), pre-scaled by 1/DOC_LEN
    const float* __restrict__ bias,  // (20,)
    const int*   __restrict__ x,     // (BATCH, 200)
    float*       __restrict__ out)   // (BATCH, 20)
{
    __shared__ int sidx[DOCS_PER_BLOCK][DOC_LEN];

    const int doc0 = blockIdx.x * DOCS_PER_BLOCK;
    const int tid  = threadIdx.x;

    for (int i = tid; i < DOCS_PER_BLOCK * DOC_LEN; i += K2_BLOCK)
        (&sidx[0][0])[i] = x[doc0 * DOC_LEN + i];
    __syncthreads();

    const int wave = tid >> 6;
    const int lane = tid & 63;
    const int doc  = doc0 + wave;
    const int g    = lane / NUM_CLASSES;          // 0..2 active, 3 idle
    const int c    = lane - g * NUM_CLASSES;

    float acc = 0.0f;
    if (g < 3) {
        #pragma unroll 4
        for (int l = g; l < DOC_LEN; l += 3) {
            const int row = sidx[wave][l];        // LDS broadcast per group
            acc += P[(size_t)row * NUM_CLASSES + c];
        }
    }

    const float a1 = __shfl(acc, lane + 20, 64);
    const float a2 = __shfl(acc, lane + 40, 64);

    float v = (lane < NUM_CLASSES) ? (acc + a1 + a2 + bias[c]) : -INFINITY;

    float m = v;
    #pragma unroll
    for (int off = 16; off > 0; off >>= 1)
        m = fmaxf(m, __shfl_xor(m, off, 32));
    const float e = (lane < NUM_CLASSES) ? expf(v - m) : 0.0f;
    float s = e;
    #pragma unroll
    for (int off = 16; off > 0; off >>= 1)
        s += __shfl_xor(s, off, 32);

    if (lane < NUM_CLASSES)
        out[doc * NUM_CLASSES + lane] = e / s;
}

extern "C" void kernel_launch(void* const* d_in, const int* in_sizes, int n_in,
                              void* d_out, int out_size, void* d_ws, size_t ws_size,
                              hipStream_t stream) {
    const float* emb  = (const float*)d_in[0];
    const float* W    = (const float*)d_in[1];
    const float* bias = (const float*)d_in[2];
    const int*   x    = (const int*)d_in[3];
    float* out = (float*)d_out;
    float* P   = (float*)d_ws;   // needs VOCAB*20*4 = 8,000,000 B

    project_kernel<<<K1_GRID, K1_BLOCK, 0, stream>>>(emb, W, P);
    pool_softmax_kernel<<<BATCH / DOCS_PER_BLOCK, K2_BLOCK, 0, stream>>>(P, bias, x, out);
}